// Round 4
// baseline (31278.851 us; speedup 1.0000x reference)
//
#include <hip/hip_runtime.h>
#include <stdint.h>

#define NN 8192
#define DD 768
#define LOG2E 1.4426950408889634f

typedef unsigned int  U32;
typedef unsigned short U16;

// monotonic float->uint key for atomicMax on floats
__device__ __forceinline__ U32 fkey(float x){
  U32 u = __float_as_uint(x);
  return (u & 0x80000000u) ? ~u : (u | 0x80000000u);
}
__device__ __forceinline__ float funkey(U32 k){
  return __uint_as_float((k & 0x80000000u) ? (k ^ 0x80000000u) : ~k);
}
__device__ __forceinline__ float ex2(float x){ return __builtin_amdgcn_exp2f(x); }
__device__ __forceinline__ float rcpf(float x){ return __builtin_amdgcn_rcpf(x); }
__device__ __forceinline__ float bflo(U32 w){ return __uint_as_float(w << 16); }
__device__ __forceinline__ float bfhi(U32 w){ return __uint_as_float(w & 0xFFFF0000u); }
// pack two floats to bf16x2 (RNE)
__device__ __forceinline__ U32 packbf(float lo, float hi){
  U32 a = __float_as_uint(lo), b = __float_as_uint(hi);
  a = a + 0x7FFFu + ((a >> 16) & 1u);
  b = b + 0x7FFFu + ((b >> 16) & 1u);
  return (a >> 16) | (b & 0xFFFF0000u);
}

// slots: 0 qmax(u32) 1 qmin(u32) 2 maxsqA key 3 maxsqB key
__global__ __launch_bounds__(64) void k_init(U32* slots){
  if (threadIdx.x == 0){ slots[0]=0u; slots[1]=0xFFFFFFFFu; slots[2]=0u; slots[3]=0u; }
}

__global__ __launch_bounds__(256) void k_sqsum(const float* __restrict__ A, const float* __restrict__ B,
                                               float* sqA, float* sqB, U32* slots){
  int wv = threadIdx.x >> 6, ln = threadIdx.x & 63;
  int row = blockIdx.x*4 + wv;
  const float* src = A; float* dst = sqA; U32* slot = slots + 2; int r = row;
  if (row >= NN){ src = B; dst = sqB; slot = slots + 3; r = row - NN; }
  const float* p = src + (size_t)r * DD;
  float s = 0.f;
  #pragma unroll
  for (int m = 0; m < DD/64; ++m){ float v = p[ln + 64*m]; s = fmaf(v, v, s); }
  #pragma unroll
  for (int o = 32; o; o >>= 1) s += __shfl_xor(s, o);
  if (ln == 0){ dst[r] = s; atomicMax(slot, fkey(s)); }
}

// 128x128 tile fp32 Gram -> dist -> u16 quantize; track qmax/qmin
__global__ __launch_bounds__(256) void k_dist(const float* __restrict__ A, const float* __restrict__ B,
                                              U16* __restrict__ q, const float* __restrict__ sqA,
                                              const float* __restrict__ sqB, U32* slots){
  __shared__ float As[16][128], Bs[16][128];
  __shared__ U32 redmx[4], redmn[4];
  const int t = threadIdx.x;
  const int i0 = blockIdx.y*128, j0 = blockIdx.x*128;
  const float S = 65535.f / (sqrtf(funkey(slots[2])) + sqrtf(funkey(slots[3])));
  float acc[8][8];
  #pragma unroll
  for (int m=0;m<8;m++)
    #pragma unroll
    for (int n=0;n<8;n++) acc[m][n] = 0.f;
  const int lr = t >> 1, lk = (t & 1)*8;
  const float* pa = A + (size_t)(i0+lr)*DD + lk;
  const float* pb = B + (size_t)(j0+lr)*DD + lk;
  const int tx = t & 15, ty = t >> 4;
  for (int k0 = 0; k0 < DD; k0 += 16){
    __syncthreads();
    float4 a0 = *(const float4*)(pa + k0);
    float4 a1 = *(const float4*)(pa + k0 + 4);
    float4 b0 = *(const float4*)(pb + k0);
    float4 b1 = *(const float4*)(pb + k0 + 4);
    As[lk+0][lr]=a0.x; As[lk+1][lr]=a0.y; As[lk+2][lr]=a0.z; As[lk+3][lr]=a0.w;
    As[lk+4][lr]=a1.x; As[lk+5][lr]=a1.y; As[lk+6][lr]=a1.z; As[lk+7][lr]=a1.w;
    Bs[lk+0][lr]=b0.x; Bs[lk+1][lr]=b0.y; Bs[lk+2][lr]=b0.z; Bs[lk+3][lr]=b0.w;
    Bs[lk+4][lr]=b1.x; Bs[lk+5][lr]=b1.y; Bs[lk+6][lr]=b1.z; Bs[lk+7][lr]=b1.w;
    __syncthreads();
    #pragma unroll
    for (int kk = 0; kk < 16; ++kk){
      float4 am0 = *(const float4*)&As[kk][ty*8];
      float4 am1 = *(const float4*)&As[kk][ty*8+4];
      float4 bn0 = *(const float4*)&Bs[kk][tx*8];
      float4 bn1 = *(const float4*)&Bs[kk][tx*8+4];
      float ar[8] = {am0.x,am0.y,am0.z,am0.w,am1.x,am1.y,am1.z,am1.w};
      float br[8] = {bn0.x,bn0.y,bn0.z,bn0.w,bn1.x,bn1.y,bn1.z,bn1.w};
      #pragma unroll
      for (int m=0;m<8;m++)
        #pragma unroll
        for (int n=0;n<8;n++) acc[m][n] = fmaf(ar[m], br[n], acc[m][n]);
    }
  }
  U32 bmax = 0u, bmin = 0xFFFFu;
  #pragma unroll
  for (int m=0;m<8;m++){
    int i = i0 + ty*8 + m;
    float sa = sqA[i];
    U16 pk[8] __attribute__((aligned(16)));
    #pragma unroll
    for (int n=0;n<8;n++){
      int j = j0 + tx*8 + n;
      float sq = sa + sqB[j] - 2.f*acc[m][n];
      float d = sqrtf(fmaxf(sq, 0.f));
      d = fmaxf(d, 1e-6f);
      U32 qv = (U32)rintf(d * S);
      if (qv > 65535u) qv = 65535u;
      bmax = bmax > qv ? bmax : qv;
      bmin = bmin < qv ? bmin : qv;
      pk[n] = (U16)qv;
    }
    *(uint4*)(q + (size_t)i*NN + j0 + tx*8) = *(const uint4*)pk;
  }
  #pragma unroll
  for (int o=32;o;o>>=1){
    U32 om = __shfl_xor(bmax, o); bmax = bmax > om ? bmax : om;
    U32 on = __shfl_xor(bmin, o); bmin = bmin < on ? bmin : on;
  }
  if ((t & 63) == 0){ redmx[t>>6] = bmax; redmn[t>>6] = bmin; }
  __syncthreads();
  if (t == 0){
    U32 mx = redmx[0], mn = redmn[0];
    #pragma unroll
    for (int i=1;i<4;i++){ mx = mx > redmx[i] ? mx : redmx[i]; mn = mn < redmn[i] ? mn : redmn[i]; }
    atomicMax(slots+0, mx); atomicMin(slots+1, mn);
  }
}

// in-place u16 q -> bf16 K' = exp(logK + s), s = 50(1+qmin/qmax) ln-units.
__global__ __launch_bounds__(256) void k_buildK(U32* K2, const U32* __restrict__ slots){
  const float qmaxf = (float)slots[0];
  const float r0n = (float)slots[1] / qmaxf;
  const float k1 = -100.f*LOG2E/qmaxf;
  const float c2 = 50.f*(1.f + r0n)*LOG2E;
  const float tcl = -1e-4f*LOG2E;
  size_t base = ((size_t)blockIdx.x*256 + threadIdx.x)*4;
  uint4 w = *(uint4*)(K2 + base);
  U32 r[4];
  U32 in[4] = {w.x, w.y, w.z, w.w};
  #pragma unroll
  for (int k=0;k<4;++k){
    float ql = (float)(in[k] & 0xFFFFu);
    float qh = (float)(in[k] >> 16);
    float el = ex2(fminf(ql*k1, tcl) + c2);
    float eh = ex2(fminf(qh*k1, tcl) + c2);
    r[k] = packbf(el, eh);
  }
  *(uint4*)(K2 + base) = make_uint4(r[0], r[1], r[2], r[3]);
}

// Fused Sinkhorn pass: block b owns rows [16b,16b+16), thread t owns cols [8t,8t+8).
// Streams K ONCE: per 4-row group computes row-dots vs v -> u_i, then accumulates
// column partials from the same registers. part[b][j] = sum_{i in panel} u_i K[i][j].
// FIRST=1: u_i = 1/8192 (initial col pass), no v read, no reductions.
template<int FIRST>
__global__ __launch_bounds__(1024, 8) void k_pass(const uint4* __restrict__ Kp,
                                                  const float* __restrict__ v,
                                                  float* __restrict__ u,
                                                  float* __restrict__ part){
  __shared__ float wavesum[4][16];
  const int t = threadIdx.x;
  const int b = blockIdx.x;
  const int r0 = b*16;
  const int wv = t >> 6, ln = t & 63;
  float vr[8];
  if (!FIRST){
    float4 v0 = *(const float4*)(v + t*8);
    float4 v1 = *(const float4*)(v + t*8 + 4);
    vr[0]=v0.x; vr[1]=v0.y; vr[2]=v0.z; vr[3]=v0.w;
    vr[4]=v1.x; vr[5]=v1.y; vr[6]=v1.z; vr[7]=v1.w;
  }
  float a[8];
  #pragma unroll
  for (int m=0;m<8;m++) a[m] = 0.f;
  #pragma unroll
  for (int g=0; g<4; ++g){
    uint4 w[4];
    #pragma unroll
    for (int r=0;r<4;++r) w[r] = Kp[(size_t)(r0 + g*4 + r)*1024 + t];
    float uu[4];
    if (!FIRST){
      if (g) __syncthreads();           // wavesum reuse hazard (prev group reads done)
      float d[4];
      #pragma unroll
      for (int r=0;r<4;++r){
        float s;
        s = bflo(w[r].x)*vr[0];
        s = fmaf(bfhi(w[r].x), vr[1], s);
        s = fmaf(bflo(w[r].y), vr[2], s);
        s = fmaf(bfhi(w[r].y), vr[3], s);
        s = fmaf(bflo(w[r].z), vr[4], s);
        s = fmaf(bfhi(w[r].z), vr[5], s);
        s = fmaf(bflo(w[r].w), vr[6], s);
        s = fmaf(bfhi(w[r].w), vr[7], s);
        d[r] = s;
      }
      #pragma unroll
      for (int o=32;o;o>>=1){
        #pragma unroll
        for (int r=0;r<4;++r) d[r] += __shfl_xor(d[r], o);
      }
      if (ln == 0){
        #pragma unroll
        for (int r=0;r<4;++r) wavesum[r][wv] = d[r];
      }
      __syncthreads();
      #pragma unroll
      for (int r=0;r<4;++r){
        float s = 0.f;
        #pragma unroll
        for (int k=0;k<16;++k) s += wavesum[r][k];
        uu[r] = rcpf(s);
      }
      if (t == 0){
        #pragma unroll
        for (int r=0;r<4;++r) u[r0 + g*4 + r] = uu[r];
      }
    } else {
      #pragma unroll
      for (int r=0;r<4;++r) uu[r] = 1.0f/8192.0f;
      if (t == 0){
        #pragma unroll
        for (int r=0;r<4;++r) u[r0 + g*4 + r] = uu[r];
      }
    }
    #pragma unroll
    for (int r=0;r<4;++r){
      float ui = uu[r];
      a[0] = fmaf(bflo(w[r].x), ui, a[0]);
      a[1] = fmaf(bfhi(w[r].x), ui, a[1]);
      a[2] = fmaf(bflo(w[r].y), ui, a[2]);
      a[3] = fmaf(bfhi(w[r].y), ui, a[3]);
      a[4] = fmaf(bflo(w[r].z), ui, a[4]);
      a[5] = fmaf(bfhi(w[r].z), ui, a[5]);
      a[6] = fmaf(bflo(w[r].w), ui, a[6]);
      a[7] = fmaf(bfhi(w[r].w), ui, a[7]);
    }
  }
  float* pp = part + (size_t)b*NN + t*8;
  *(float4*)pp     = make_float4(a[0],a[1],a[2],a[3]);
  *(float4*)(pp+4) = make_float4(a[4],a[5],a[6],a[7]);
}

// v[j] = 1 / sum_{b<512} part[b][j]
__global__ __launch_bounds__(128) void k_vred(const float* __restrict__ part, float* __restrict__ v){
  const int c = blockIdx.x*128 + threadIdx.x;
  float s = 0.f;
  #pragma unroll 8
  for (int k = 0; k < 512; ++k) s += part[(size_t)k*NN + c];
  v[c] = rcpf(s);
}

// aligned_A[i][d] = u_i * sum_j K'[i][j] * (v'_j * A[j][d])
__global__ __launch_bounds__(256) void k_outA(const U16* __restrict__ Kp, const float* __restrict__ A,
                                              const float* __restrict__ u, const float* __restrict__ v,
                                              float* __restrict__ outA){
  __shared__ float T[64][64];
  const int t = threadIdx.x;
  const int i0 = blockIdx.y*64, d0 = blockIdx.x*128;
  const int jc = t & 63, ig = t >> 6;
  const int dg = t & 31, ig2 = t >> 5;
  float4 acc[8];
  #pragma unroll
  for (int m=0;m<8;m++) acc[m] = make_float4(0.f,0.f,0.f,0.f);
  for (int j0 = 0; j0 < NN; j0 += 64){
    __syncthreads();
    float vv = v[j0 + jc];
    #pragma unroll
    for (int m=0;m<16;m++){
      int i = i0 + ig*16 + m;
      U32 kb = ((U32)Kp[(size_t)i*NN + j0 + jc]) << 16;
      T[ig*16+m][jc] = __uint_as_float(kb) * vv;
    }
    __syncthreads();
    #pragma unroll 4
    for (int jj = 0; jj < 64; ++jj){
      float4 a4 = *(const float4*)(A + (size_t)(j0+jj)*DD + d0 + dg*4);
      #pragma unroll
      for (int m=0;m<8;m++){
        float tv = T[ig2*8+m][jj];
        acc[m].x = fmaf(tv, a4.x, acc[m].x);
        acc[m].y = fmaf(tv, a4.y, acc[m].y);
        acc[m].z = fmaf(tv, a4.z, acc[m].z);
        acc[m].w = fmaf(tv, a4.w, acc[m].w);
      }
    }
  }
  #pragma unroll
  for (int m=0;m<8;m++){
    int i = i0 + ig2*8 + m;
    float ui = u[i];
    acc[m].x *= ui; acc[m].y *= ui; acc[m].z *= ui; acc[m].w *= ui;
    *(float4*)(outA + (size_t)i*DD + d0 + dg*4) = acc[m];
  }
}

// aligned_B[j][d] = v'_j * sum_i (u_i * K'[i][j]) * B[i][d]
__global__ __launch_bounds__(256) void k_outB(const U16* __restrict__ Kp, const float* __restrict__ B,
                                              const float* __restrict__ u, const float* __restrict__ v,
                                              float* __restrict__ outB){
  __shared__ float Tt[64][65];
  const int t = threadIdx.x;
  const int j0t = blockIdx.y*64, d0 = blockIdx.x*128;
  const int jc = t & 63, ig = t >> 6;
  const int dg = t & 31, jg = t >> 5;
  float4 acc[8];
  #pragma unroll
  for (int m=0;m<8;m++) acc[m] = make_float4(0.f,0.f,0.f,0.f);
  for (int i0 = 0; i0 < NN; i0 += 64){
    __syncthreads();
    #pragma unroll
    for (int m=0;m<16;m++){
      int i = i0 + ig*16 + m;
      U32 kb = ((U32)Kp[(size_t)i*NN + j0t + jc]) << 16;
      Tt[jc][ig*16+m] = __uint_as_float(kb) * u[i];
    }
    __syncthreads();
    #pragma unroll 4
    for (int ii = 0; ii < 64; ++ii){
      float4 b4 = *(const float4*)(B + (size_t)(i0+ii)*DD + d0 + dg*4);
      #pragma unroll
      for (int m=0;m<8;m++){
        float tv = Tt[jg*8+m][ii];
        acc[m].x = fmaf(tv, b4.x, acc[m].x);
        acc[m].y = fmaf(tv, b4.y, acc[m].y);
        acc[m].z = fmaf(tv, b4.z, acc[m].z);
        acc[m].w = fmaf(tv, b4.w, acc[m].w);
      }
    }
  }
  #pragma unroll
  for (int m=0;m<8;m++){
    int j = j0t + jg*8 + m;
    float vj = v[j];
    acc[m].x *= vj; acc[m].y *= vj; acc[m].z *= vj; acc[m].w *= vj;
    *(float4*)(outB + (size_t)j*DD + d0 + dg*4) = acc[m];
  }
}

extern "C" void kernel_launch(void* const* d_in, const int* in_sizes, int n_in,
                              void* d_out, int out_size, void* d_ws, size_t ws_size,
                              hipStream_t stream) {
  const float* A = (const float*)d_in[0];
  const float* B = (const float*)d_in[1];
  float* out = (float*)d_out;
  char* ws = (char*)d_ws;
  U16*  q     = (U16*) (ws);                          // 8192*8192*2 = 134217728
  float* u    = (float*)(ws + 136314880);             // 32768
  float* v    = (float*)(ws + 136347648);             // 32768
  float* sqA  = (float*)(ws + 136380416);             // 32768
  float* sqB  = (float*)(ws + 136413184);             // 32768
  U32*  slots = (U32*) (ws + 136445952);              // scalars
  float* part = out;                                  // 512*8192*4 = 16.8 MB scratch in d_out

  k_init<<<1, 64, 0, stream>>>(slots);
  k_sqsum<<<4096, 256, 0, stream>>>(A, B, sqA, sqB, slots);
  k_dist<<<dim3(64,64), 256, 0, stream>>>(A, B, q, sqA, sqB, slots);
  k_buildK<<<32768, 256, 0, stream>>>((U32*)q, slots);

  const uint4* Kp4 = (const uint4*)q;
  k_pass<1><<<512, 1024, 0, stream>>>(Kp4, v, u, part);
  for (int it = 0; it < 200; ++it){
    k_vred<<<64, 128, 0, stream>>>(part, v);
    k_pass<0><<<512, 1024, 0, stream>>>(Kp4, v, u, part);
  }
  k_outA<<<dim3(6,128), 256, 0, stream>>>(q, A, u, v, out);
  k_outB<<<dim3(6,128), 256, 0, stream>>>(q, B, u, v, out + (size_t)NN*DD);
}

// Round 6
// 23906.549 us; speedup vs baseline: 1.3084x; 1.3084x over previous
//
#include <hip/hip_runtime.h>
#include <stdint.h>

#define NN 8192
#define DD 768
#define LOG2E 1.4426950408889634f

typedef unsigned int  U32;
typedef unsigned short U16;
typedef __attribute__((ext_vector_type(8))) short short8;
typedef __attribute__((ext_vector_type(4))) float f32x4;

__device__ __forceinline__ U32 fkey(float x){
  U32 u = __float_as_uint(x);
  return (u & 0x80000000u) ? ~u : (u | 0x80000000u);
}
__device__ __forceinline__ float funkey(U32 k){
  return __uint_as_float((k & 0x80000000u) ? (k ^ 0x80000000u) : ~k);
}
__device__ __forceinline__ float ex2(float x){ return __builtin_amdgcn_exp2f(x); }
__device__ __forceinline__ float rcpf(float x){ return __builtin_amdgcn_rcpf(x); }
__device__ __forceinline__ float bflo(U32 w){ return __uint_as_float(w << 16); }
__device__ __forceinline__ float bfhi(U32 w){ return __uint_as_float(w & 0xFFFF0000u); }
__device__ __forceinline__ U16 tobf(float x){
  U32 a = __float_as_uint(x);
  return (U16)((a + 0x7FFFu + ((a >> 16) & 1u)) >> 16);
}
__device__ __forceinline__ U32 packbf(float lo, float hi){
  U32 a = __float_as_uint(lo), b = __float_as_uint(hi);
  a = a + 0x7FFFu + ((a >> 16) & 1u);
  b = b + 0x7FFFu + ((b >> 16) & 1u);
  return (a >> 16) | (b & 0xFFFF0000u);
}

// slots: 0 qmax 1 qmin 2 maxsqA key 3 maxsqB key ; slots[4..11] = per-cc tail counters
__global__ __launch_bounds__(64) void k_init(float* u, U32* slots){
  int t = threadIdx.x;
  if (t == 0){ slots[0]=0u; slots[1]=0xFFFFFFFFu; slots[2]=0u; slots[3]=0u; }
  if (t >= 4 && t < 12) slots[t] = 0u;
}
__global__ __launch_bounds__(256) void k_useti(float* u){
  int t = blockIdx.x*256 + threadIdx.x;
  if (t < NN) u[t] = 1.0f/8192.0f;
}

__global__ __launch_bounds__(256) void k_sqsum(const float* __restrict__ A, const float* __restrict__ B,
                                               float* sqA, float* sqB, U32* slots){
  int wv = threadIdx.x >> 6, ln = threadIdx.x & 63;
  int row = blockIdx.x*4 + wv;
  const float* src = A; float* dst = sqA; U32* slot = slots + 2; int r = row;
  if (row >= NN){ src = B; dst = sqB; slot = slots + 3; r = row - NN; }
  const float* p = src + (size_t)r * DD;
  float s = 0.f;
  #pragma unroll
  for (int m = 0; m < DD/64; ++m){ float v = p[ln + 64*m]; s = fmaf(v, v, s); }
  #pragma unroll
  for (int o = 32; o; o >>= 1) s += __shfl_xor(s, o);
  if (ln == 0){ dst[r] = s; atomicMax(slot, fkey(s)); }
}

// 128x128 tile fp32 Gram -> dist -> u16 quantize; track qmax/qmin
__global__ __launch_bounds__(256) void k_dist(const float* __restrict__ A, const float* __restrict__ B,
                                              U16* __restrict__ q, const float* __restrict__ sqA,
                                              const float* __restrict__ sqB, U32* slots){
  __shared__ float As[16][128], Bs[16][128];
  __shared__ U32 redmx[4], redmn[4];
  const int t = threadIdx.x;
  const int i0 = blockIdx.y*128, j0 = blockIdx.x*128;
  const float S = 65535.f / (sqrtf(funkey(slots[2])) + sqrtf(funkey(slots[3])));
  float acc[8][8];
  #pragma unroll
  for (int m=0;m<8;m++)
    #pragma unroll
    for (int n=0;n<8;n++) acc[m][n] = 0.f;
  const int lr = t >> 1, lk = (t & 1)*8;
  const float* pa = A + (size_t)(i0+lr)*DD + lk;
  const float* pb = B + (size_t)(j0+lr)*DD + lk;
  const int tx = t & 15, ty = t >> 4;
  for (int k0 = 0; k0 < DD; k0 += 16){
    __syncthreads();
    float4 a0 = *(const float4*)(pa + k0);
    float4 a1 = *(const float4*)(pa + k0 + 4);
    float4 b0 = *(const float4*)(pb + k0);
    float4 b1 = *(const float4*)(pb + k0 + 4);
    As[lk+0][lr]=a0.x; As[lk+1][lr]=a0.y; As[lk+2][lr]=a0.z; As[lk+3][lr]=a0.w;
    As[lk+4][lr]=a1.x; As[lk+5][lr]=a1.y; As[lk+6][lr]=a1.z; As[lk+7][lr]=a1.w;
    Bs[lk+0][lr]=b0.x; Bs[lk+1][lr]=b0.y; Bs[lk+2][lr]=b0.z; Bs[lk+3][lr]=b0.w;
    Bs[lk+4][lr]=b1.x; Bs[lk+5][lr]=b1.y; Bs[lk+6][lr]=b1.z; Bs[lk+7][lr]=b1.w;
    __syncthreads();
    #pragma unroll
    for (int kk = 0; kk < 16; ++kk){
      float4 am0 = *(const float4*)&As[kk][ty*8];
      float4 am1 = *(const float4*)&As[kk][ty*8+4];
      float4 bn0 = *(const float4*)&Bs[kk][tx*8];
      float4 bn1 = *(const float4*)&Bs[kk][tx*8+4];
      float ar[8] = {am0.x,am0.y,am0.z,am0.w,am1.x,am1.y,am1.z,am1.w};
      float br[8] = {bn0.x,bn0.y,bn0.z,bn0.w,bn1.x,bn1.y,bn1.z,bn1.w};
      #pragma unroll
      for (int m=0;m<8;m++)
        #pragma unroll
        for (int n=0;n<8;n++) acc[m][n] = fmaf(ar[m], br[n], acc[m][n]);
    }
  }
  U32 bmax = 0u, bmin = 0xFFFFu;
  #pragma unroll
  for (int m=0;m<8;m++){
    int i = i0 + ty*8 + m;
    float sa = sqA[i];
    U16 pk[8] __attribute__((aligned(16)));
    #pragma unroll
    for (int n=0;n<8;n++){
      int j = j0 + tx*8 + n;
      float sq = sa + sqB[j] - 2.f*acc[m][n];
      float d = sqrtf(fmaxf(sq, 0.f));
      d = fmaxf(d, 1e-6f);
      U32 qv = (U32)rintf(d * S);
      if (qv > 65535u) qv = 65535u;
      bmax = bmax > qv ? bmax : qv;
      bmin = bmin < qv ? bmin : qv;
      pk[n] = (U16)qv;
    }
    *(uint4*)(q + (size_t)i*NN + j0 + tx*8) = *(const uint4*)pk;
  }
  #pragma unroll
  for (int o=32;o;o>>=1){
    U32 om = __shfl_xor(bmax, o); bmax = bmax > om ? bmax : om;
    U32 on = __shfl_xor(bmin, o); bmin = bmin < on ? bmin : on;
  }
  if ((t & 63) == 0){ redmx[t>>6] = bmax; redmn[t>>6] = bmin; }
  __syncthreads();
  if (t == 0){
    U32 mx = redmx[0], mn = redmn[0];
    #pragma unroll
    for (int i=1;i<4;i++){ mx = mx > redmx[i] ? mx : redmx[i]; mn = mn < redmn[i] ? mn : redmn[i]; }
    atomicMax(slots+0, mx); atomicMin(slots+1, mn);
  }
}

// in-place u16 q -> bf16 K' = exp(logK + s)
__global__ __launch_bounds__(256) void k_buildK(U32* K2, const U32* __restrict__ slots){
  const float qmaxf = (float)slots[0];
  const float r0n = (float)slots[1] / qmaxf;
  const float k1 = -100.f*LOG2E/qmaxf;
  const float c2 = 50.f*(1.f + r0n)*LOG2E;
  const float tcl = -1e-4f*LOG2E;
  size_t base = ((size_t)blockIdx.x*256 + threadIdx.x)*4;
  uint4 w = *(uint4*)(K2 + base);
  U32 r[4];
  U32 in[4] = {w.x, w.y, w.z, w.w};
  #pragma unroll
  for (int k=0;k<4;++k){
    float ql = (float)(in[k] & 0xFFFFu);
    float qh = (float)(in[k] >> 16);
    float el = ex2(fminf(ql*k1, tcl) + c2);
    float eh = ex2(fminf(qh*k1, tcl) + c2);
    r[k] = packbf(el, eh);
  }
  *(uint4*)(K2 + base) = make_uint4(r[0], r[1], r[2], r[3]);
}

// col partials + fused tail-block v reduction per column slice.
__global__ __launch_bounds__(256) void k_colv(const U32* __restrict__ K2, const float* __restrict__ u,
                                              float* __restrict__ part, float* __restrict__ v,
                                              U32* ctr){
  __shared__ float ul[128];
  __shared__ int lastFlag;
  const int t = threadIdx.x;
  const int cc = blockIdx.x;          // 8 chunks of 1024 cols
  const int rc = blockIdx.y;          // 64 chunks of 128 rows
  const int r0 = rc*128;
  if (t < 128) ul[t] = u[r0 + t];
  __syncthreads();
  float a0=0.f, a1=0.f, a2=0.f, a3=0.f;
  const U32* p = K2 + (size_t)r0*(NN/2) + cc*512 + t*2;
  #pragma unroll 8
  for (int i = 0; i < 128; ++i){
    uint2 w = *(const uint2*)(p + (size_t)i*(NN/2));
    float ui = ul[i];
    a0 = fmaf(bflo(w.x), ui, a0);
    a1 = fmaf(bfhi(w.x), ui, a1);
    a2 = fmaf(bflo(w.y), ui, a2);
    a3 = fmaf(bfhi(w.y), ui, a3);
  }
  *(float4*)(part + (size_t)rc*NN + cc*1024 + t*4) = make_float4(a0,a1,a2,a3);
  // tail-block: last block of this column slice reduces part -> v
  __threadfence();
  __syncthreads();
  if (t == 0){
    U32 prev = atomicAdd(&ctr[cc], 1u);
    lastFlag = (prev == 63u) ? 1 : 0;
  }
  __syncthreads();
  if (lastFlag){
    __threadfence();
    const int c = cc*1024 + t*4;
    float s0=0.f, s1=0.f, s2=0.f, s3=0.f;
    #pragma unroll 8
    for (int k = 0; k < 64; ++k){
      float4 p4 = *(const float4*)(part + (size_t)k*NN + c);
      s0 += p4.x; s1 += p4.y; s2 += p4.z; s3 += p4.w;
    }
    *(float4*)(v + c) = make_float4(rcpf(s0), rcpf(s1), rcpf(s2), rcpf(s3));
    if (t == 0) ctr[cc] = 0;
  }
}

// row pass (serpentine: reversed block order); u = 1/(K v)
__global__ __launch_bounds__(512) void k_row(const U32* __restrict__ K2, const float* __restrict__ v,
                                             float* __restrict__ u){
  __shared__ float vl[NN];
  const int t = threadIdx.x;
  #pragma unroll
  for (int h = 0; h < 4; ++h) ((float4*)vl)[t + 512*h] = ((const float4*)v)[t + 512*h];
  __syncthreads();
  const int wv = t >> 6, ln = t & 63;
  const int r = (1023 - (int)blockIdx.x)*8 + wv;   // reversed sweep
  const uint4* p = (const uint4*)(K2 + (size_t)r*(NN/2));
  float s = 0.f;
  #pragma unroll 4
  for (int k = 0; k < 16; ++k){
    uint4 w = p[k*64 + ln];
    float4 v0 = *(const float4*)&vl[(k*64+ln)*8];
    float4 v1 = *(const float4*)&vl[(k*64+ln)*8 + 4];
    s = fmaf(bflo(w.x), v0.x, s); s = fmaf(bfhi(w.x), v0.y, s);
    s = fmaf(bflo(w.y), v0.z, s); s = fmaf(bfhi(w.y), v0.w, s);
    s = fmaf(bflo(w.z), v1.x, s); s = fmaf(bfhi(w.z), v1.y, s);
    s = fmaf(bflo(w.w), v1.z, s); s = fmaf(bfhi(w.w), v1.w, s);
  }
  #pragma unroll
  for (int o = 32; o; o >>= 1) s += __shfl_xor(s, o);
  if (ln == 0) u[r] = rcpf(s);
}

// At_h/At_l[d][j] = bf16 hi/lo split of v_j * A[j][d]  (transposed, j-fast)
__global__ __launch_bounds__(256) void k_At(const float* __restrict__ A, const float* __restrict__ v,
                                            U16* __restrict__ Ath, U16* __restrict__ Atl){
  __shared__ float Ts[64][65];
  const int t = threadIdx.x;
  const int d0 = blockIdx.x*64, j0 = blockIdx.y*64;
  {
    const int r = t >> 2, cs = (t & 3)*16;
    const float vj = v[j0 + r];
    #pragma unroll
    for (int e=0;e<4;++e){
      float4 a4 = *(const float4*)(A + (size_t)(j0+r)*DD + d0 + cs + e*4);
      Ts[r][cs+e*4+0]=a4.x*vj; Ts[r][cs+e*4+1]=a4.y*vj;
      Ts[r][cs+e*4+2]=a4.z*vj; Ts[r][cs+e*4+3]=a4.w*vj;
    }
  }
  __syncthreads();
  {
    const int dr = t >> 2, jseg = t & 3;
    U16 hh[16], ll[16];
    #pragma unroll
    for (int e=0;e<16;++e){
      float x = Ts[jseg*16+e][dr];
      U16 h = tobf(x);
      hh[e] = h;
      ll[e] = tobf(x - __uint_as_float(((U32)h) << 16));
    }
    size_t off = (size_t)(d0+dr)*NN + j0 + jseg*16;
    *(uint4*)(Ath + off)     = *(const uint4*)&hh[0];
    *(uint4*)(Ath + off + 8) = *(const uint4*)&hh[8];
    *(uint4*)(Atl + off)     = *(const uint4*)&ll[0];
    *(uint4*)(Atl + off + 8) = *(const uint4*)&ll[8];
  }
}

// MFMA out-GEMM: aligned_A[i][d] = u_i * sum_j K'[i][j] * (At_h+At_l)[d][j]
// block: 512 thr = 8 waves (4 M x 2 N); tile M=128, N=192; K-step 32 over j.
__global__ __launch_bounds__(512) void k_outA(const U16* __restrict__ Kp,
                                              const U16* __restrict__ Ath, const U16* __restrict__ Atl,
                                              const float* __restrict__ u, float* __restrict__ outA){
  __shared__ U16 Ks[128][40];
  __shared__ U16 Ah[192][40];
  __shared__ U16 Al[192][40];
  const int t = threadIdx.x;
  const int i0 = blockIdx.y*128, d0 = blockIdx.x*192;
  const int w  = t >> 6, lane = t & 63;
  const int wm = w >> 1, wn = w & 1;
  const int l15 = lane & 15, lhi = lane >> 4;
  f32x4 acc[2][6];
  #pragma unroll
  for (int fm=0;fm<2;++fm)
    #pragma unroll
    for (int fn=0;fn<6;++fn) acc[fm][fn] = (f32x4){0.f,0.f,0.f,0.f};

  const int sr = t >> 2, sseg = t & 3;          // K' staging: 128 rows x 4 segs
  for (int j0 = 0; j0 < NN; j0 += 32){
    __syncthreads();
    {
      uint4 kw = *(const uint4*)(Kp + (size_t)(i0+sr)*NN + j0 + sseg*8);
      *(uint4*)&Ks[sr][sseg*8] = kw;
      // Ah: ids 0..767 (192 rows x 4 segs); Al: ids 768..1535.
      #pragma unroll
      for (int uu=0; uu<3; ++uu){
        int id = t + 512*uu;
        if (id < 768){
          int r = id >> 2, seg = id & 3;
          uint4 aw = *(const uint4*)(Ath + (size_t)(d0+r)*NN + j0 + seg*8);
          *(uint4*)&Ah[r][seg*8] = aw;
        } else {
          int rid = id - 768;
          int r = rid >> 2, seg = rid & 3;
          uint4 aw = *(const uint4*)(Atl + (size_t)(d0+r)*NN + j0 + seg*8);
          *(uint4*)&Al[r][seg*8] = aw;
        }
      }
    }
    __syncthreads();
    short8 af[2];
    #pragma unroll
    for (int fm=0;fm<2;++fm)
      af[fm] = *(const short8*)&Ks[wm*32 + fm*16 + l15][lhi*8];
    #pragma unroll
    for (int fn=0;fn<6;++fn){
      short8 bh = *(const short8*)&Ah[wn*96 + fn*16 + l15][lhi*8];
      short8 bl = *(const short8*)&Al[wn*96 + fn*16 + l15][lhi*8];
      #pragma unroll
      for (int fm=0;fm<2;++fm){
        acc[fm][fn] = __builtin_amdgcn_mfma_f32_16x16x32_bf16(af[fm], bh, acc[fm][fn], 0, 0, 0);
        acc[fm][fn] = __builtin_amdgcn_mfma_f32_16x16x32_bf16(af[fm], bl, acc[fm][fn], 0, 0, 0);
      }
    }
  }
  float us[2][4];
  #pragma unroll
  for (int fm=0;fm<2;++fm)
    #pragma unroll
    for (int r=0;r<4;++r) us[fm][r] = u[i0 + wm*32 + fm*16 + lhi*4 + r];
  #pragma unroll
  for (int fm=0;fm<2;++fm)
    #pragma unroll
    for (int fn=0;fn<6;++fn)
      #pragma unroll
      for (int r=0;r<4;++r){
        int i = i0 + wm*32 + fm*16 + lhi*4 + r;
        int d = d0 + wn*96 + fn*16 + l15;
        outA[(size_t)i*DD + d] = acc[fm][fn][r] * us[fm][r];
      }
}

// VALU out-GEMM: aligned_B[j][d] = v_j * sum_i (u_i K'[i][j]) * B[i][d]
__global__ __launch_bounds__(256) void k_outB(const U16* __restrict__ Kp, const float* __restrict__ B,
                                              const float* __restrict__ u, const float* __restrict__ v,
                                              float* __restrict__ outB){
  __shared__ float Tt[64][65];
  const int t = threadIdx.x;
  const int j0t = blockIdx.y*64, d0 = blockIdx.x*128;
  const int jc = t & 63, ig = t >> 6;
  const int dg = t & 31, jg = t >> 5;
  float4 acc[8];
  #pragma unroll
  for (int m=0;m<8;m++) acc[m] = make_float4(0.f,0.f,0.f,0.f);
  for (int i0 = 0; i0 < NN; i0 += 64){
    __syncthreads();
    #pragma unroll
    for (int m=0;m<16;m++){
      int i = i0 + ig*16 + m;
      U32 kb = ((U32)Kp[(size_t)i*NN + j0t + jc]) << 16;
      Tt[jc][ig*16+m] = __uint_as_float(kb) * u[i];
    }
    __syncthreads();
    #pragma unroll 4
    for (int ii = 0; ii < 64; ++ii){
      float4 b4 = *(const float4*)(B + (size_t)(i0+ii)*DD + d0 + dg*4);
      #pragma unroll
      for (int m=0;m<8;m++){
        float tv = Tt[jg*8+m][ii];
        acc[m].x = fmaf(tv, b4.x, acc[m].x);
        acc[m].y = fmaf(tv, b4.y, acc[m].y);
        acc[m].z = fmaf(tv, b4.z, acc[m].z);
        acc[m].w = fmaf(tv, b4.w, acc[m].w);
      }
    }
  }
  #pragma unroll
  for (int m=0;m<8;m++){
    int j = j0t + jg*8 + m;
    float vj = v[j];
    acc[m].x *= vj; acc[m].y *= vj; acc[m].z *= vj; acc[m].w *= vj;
    *(float4*)(outB + (size_t)j*DD + d0 + dg*4) = acc[m];
  }
}

extern "C" void kernel_launch(void* const* d_in, const int* in_sizes, int n_in,
                              void* d_out, int out_size, void* d_ws, size_t ws_size,
                              hipStream_t stream) {
  const float* A = (const float*)d_in[0];
  const float* B = (const float*)d_in[1];
  float* out = (float*)d_out;
  char* ws = (char*)d_ws;
  U16*  q     = (U16*) (ws);                          // 134217728 B
  float* part = (float*)(ws + 134217728);             // 64*8192*4 = 2 MB
  float* u    = (float*)(ws + 136314880);
  float* v    = (float*)(ws + 136347648);
  float* sqA  = (float*)(ws + 136380416);
  float* sqB  = (float*)(ws + 136413184);
  U32*  slots = (U32*) (ws + 136445952);              // 4 scalars + 8 tail counters
  // At scratch lives in d_out's second half (dead until k_outB writes it):
  U16* Ath = (U16*)(out + (size_t)NN*DD);             // bytes [25.2MB, 37.8MB)
  U16* Atl = Ath + (size_t)NN*DD;                     // bytes [37.8MB, 50.3MB)

  k_init<<<1, 64, 0, stream>>>(u, slots);
  k_useti<<<32, 256, 0, stream>>>(u);
  k_sqsum<<<4096, 256, 0, stream>>>(A, B, sqA, sqB, slots);
  k_dist<<<dim3(64,64), 256, 0, stream>>>(A, B, q, sqA, sqB, slots);
  k_buildK<<<32768, 256, 0, stream>>>((U32*)q, slots);

  for (int it = 0; it < 200; ++it){
    k_colv<<<dim3(8,64), 256, 0, stream>>>((const U32*)q, u, part, v, slots + 4);
    k_row<<<1024, 512, 0, stream>>>((const U32*)q, v, u);
  }

  k_At<<<dim3(12,128), 256, 0, stream>>>(A, v, Ath, Atl);
  k_outA<<<dim3(4,64), 512, 0, stream>>>(q, Ath, Atl, u, out);
  k_outB<<<dim3(6,128), 256, 0, stream>>>(q, B, u, v, out + (size_t)NN*DD);
}

// Round 8
// 13346.240 us; speedup vs baseline: 2.3436x; 1.7913x over previous
//
#include <hip/hip_runtime.h>
#include <stdint.h>

#define NN 8192
#define DD 768
#define LOG2E 1.4426950408889634f

typedef unsigned int  U32;
typedef unsigned short U16;
typedef __attribute__((ext_vector_type(8))) short short8;
typedef __attribute__((ext_vector_type(4))) float f32x4;

__device__ __forceinline__ U32 fkey(float x){
  U32 u = __float_as_uint(x);
  return (u & 0x80000000u) ? ~u : (u | 0x80000000u);
}
__device__ __forceinline__ float funkey(U32 k){
  return __uint_as_float((k & 0x80000000u) ? (k ^ 0x80000000u) : ~k);
}
__device__ __forceinline__ float ex2(float x){ return __builtin_amdgcn_exp2f(x); }
__device__ __forceinline__ float rcpf(float x){ return __builtin_amdgcn_rcpf(x); }
__device__ __forceinline__ float bflo(U32 w){ return __uint_as_float(w << 16); }
__device__ __forceinline__ float bfhi(U32 w){ return __uint_as_float(w & 0xFFFF0000u); }
__device__ __forceinline__ U16 tobf(float x){
  U32 a = __float_as_uint(x);
  return (U16)((a + 0x7FFFu + ((a >> 16) & 1u)) >> 16);
}
__device__ __forceinline__ U32 packbf(float lo, float hi){
  U32 a = __float_as_uint(lo), b = __float_as_uint(hi);
  a = a + 0x7FFFu + ((a >> 16) & 1u);
  b = b + 0x7FFFu + ((b >> 16) & 1u);
  return (a >> 16) | (b & 0xFFFF0000u);
}

// slots: 0 qmax 1 qmin 2 maxsqA key 3 maxsqB key
__global__ __launch_bounds__(64) void k_init(U32* slots){
  if (threadIdx.x == 0){ slots[0]=0u; slots[1]=0xFFFFFFFFu; slots[2]=0u; slots[3]=0u; }
}
__global__ __launch_bounds__(256) void k_useti(float* u){
  int t = blockIdx.x*256 + threadIdx.x;
  if (t < NN) u[t] = 1.0f/8192.0f;
}

__global__ __launch_bounds__(256) void k_sqsum(const float* __restrict__ A, const float* __restrict__ B,
                                               float* sqA, float* sqB, U32* slots){
  int wv = threadIdx.x >> 6, ln = threadIdx.x & 63;
  int row = blockIdx.x*4 + wv;
  const float* src = A; float* dst = sqA; U32* slot = slots + 2; int r = row;
  if (row >= NN){ src = B; dst = sqB; slot = slots + 3; r = row - NN; }
  const float* p = src + (size_t)r * DD;
  float s = 0.f;
  #pragma unroll
  for (int m = 0; m < DD/64; ++m){ float v = p[ln + 64*m]; s = fmaf(v, v, s); }
  #pragma unroll
  for (int o = 32; o; o >>= 1) s += __shfl_xor(s, o);
  if (ln == 0){ dst[r] = s; atomicMax(slot, fkey(s)); }
}

// 128x128 tile fp32 Gram -> dist -> u16 quantize; track qmax/qmin
__global__ __launch_bounds__(256) void k_dist(const float* __restrict__ A, const float* __restrict__ B,
                                              U16* __restrict__ q, const float* __restrict__ sqA,
                                              const float* __restrict__ sqB, U32* slots){
  __shared__ float As[16][128], Bs[16][128];
  __shared__ U32 redmx[4], redmn[4];
  const int t = threadIdx.x;
  const int i0 = blockIdx.y*128, j0 = blockIdx.x*128;
  const float S = 65535.f / (sqrtf(funkey(slots[2])) + sqrtf(funkey(slots[3])));
  float acc[8][8];
  #pragma unroll
  for (int m=0;m<8;m++)
    #pragma unroll
    for (int n=0;n<8;n++) acc[m][n] = 0.f;
  const int lr = t >> 1, lk = (t & 1)*8;
  const float* pa = A + (size_t)(i0+lr)*DD + lk;
  const float* pb = B + (size_t)(j0+lr)*DD + lk;
  const int tx = t & 15, ty = t >> 4;
  for (int k0 = 0; k0 < DD; k0 += 16){
    __syncthreads();
    float4 a0 = *(const float4*)(pa + k0);
    float4 a1 = *(const float4*)(pa + k0 + 4);
    float4 b0 = *(const float4*)(pb + k0);
    float4 b1 = *(const float4*)(pb + k0 + 4);
    As[lk+0][lr]=a0.x; As[lk+1][lr]=a0.y; As[lk+2][lr]=a0.z; As[lk+3][lr]=a0.w;
    As[lk+4][lr]=a1.x; As[lk+5][lr]=a1.y; As[lk+6][lr]=a1.z; As[lk+7][lr]=a1.w;
    Bs[lk+0][lr]=b0.x; Bs[lk+1][lr]=b0.y; Bs[lk+2][lr]=b0.z; Bs[lk+3][lr]=b0.w;
    Bs[lk+4][lr]=b1.x; Bs[lk+5][lr]=b1.y; Bs[lk+6][lr]=b1.z; Bs[lk+7][lr]=b1.w;
    __syncthreads();
    #pragma unroll
    for (int kk = 0; kk < 16; ++kk){
      float4 am0 = *(const float4*)&As[kk][ty*8];
      float4 am1 = *(const float4*)&As[kk][ty*8+4];
      float4 bn0 = *(const float4*)&Bs[kk][tx*8];
      float4 bn1 = *(const float4*)&Bs[kk][tx*8+4];
      float ar[8] = {am0.x,am0.y,am0.z,am0.w,am1.x,am1.y,am1.z,am1.w};
      float br[8] = {bn0.x,bn0.y,bn0.z,bn0.w,bn1.x,bn1.y,bn1.z,bn1.w};
      #pragma unroll
      for (int m=0;m<8;m++)
        #pragma unroll
        for (int n=0;n<8;n++) acc[m][n] = fmaf(ar[m], br[n], acc[m][n]);
    }
  }
  U32 bmax = 0u, bmin = 0xFFFFu;
  #pragma unroll
  for (int m=0;m<8;m++){
    int i = i0 + ty*8 + m;
    float sa = sqA[i];
    U16 pk[8] __attribute__((aligned(16)));
    #pragma unroll
    for (int n=0;n<8;n++){
      int j = j0 + tx*8 + n;
      float sq = sa + sqB[j] - 2.f*acc[m][n];
      float d = sqrtf(fmaxf(sq, 0.f));
      d = fmaxf(d, 1e-6f);
      U32 qv = (U32)rintf(d * S);
      if (qv > 65535u) qv = 65535u;
      bmax = bmax > qv ? bmax : qv;
      bmin = bmin < qv ? bmin : qv;
      pk[n] = (U16)qv;
    }
    *(uint4*)(q + (size_t)i*NN + j0 + tx*8) = *(const uint4*)pk;
  }
  #pragma unroll
  for (int o=32;o;o>>=1){
    U32 om = __shfl_xor(bmax, o); bmax = bmax > om ? bmax : om;
    U32 on = __shfl_xor(bmin, o); bmin = bmin < on ? bmin : on;
  }
  if ((t & 63) == 0){ redmx[t>>6] = bmax; redmn[t>>6] = bmin; }
  __syncthreads();
  if (t == 0){
    U32 mx = redmx[0], mn = redmn[0];
    #pragma unroll
    for (int i=1;i<4;i++){ mx = mx > redmx[i] ? mx : redmx[i]; mn = mn < redmn[i] ? mn : redmn[i]; }
    atomicMax(slots+0, mx); atomicMin(slots+1, mn);
  }
}

// in-place u16 q -> bf16 K' = exp(logK + s), s = 50(1+qmin/qmax) ln-units
__global__ __launch_bounds__(256) void k_buildK(U32* K2, const U32* __restrict__ slots){
  const float qmaxf = (float)slots[0];
  const float r0n = (float)slots[1] / qmaxf;
  const float k1 = -100.f*LOG2E/qmaxf;
  const float c2 = 50.f*(1.f + r0n)*LOG2E;
  const float tcl = -1e-4f*LOG2E;
  size_t base = ((size_t)blockIdx.x*256 + threadIdx.x)*4;
  uint4 w = *(uint4*)(K2 + base);
  U32 r[4];
  U32 in[4] = {w.x, w.y, w.z, w.w};
  #pragma unroll
  for (int k=0;k<4;++k){
    float ql = (float)(in[k] & 0xFFFFu);
    float qh = (float)(in[k] >> 16);
    float el = ex2(fminf(ql*k1, tcl) + c2);
    float eh = ex2(fminf(qh*k1, tcl) + c2);
    r[k] = packbf(el, eh);
  }
  *(uint4*)(K2 + base) = make_uint4(r[0], r[1], r[2], r[3]);
}

// ---------------- loop kernels (R2-proven structure) ----------------
// col partials: part[rc][j] = sum_{i in 128-row chunk rc} K'[i][j] * u[i]
__global__ __launch_bounds__(256) void k_col(const U32* __restrict__ K2, const float* __restrict__ u,
                                             float* __restrict__ part){
  __shared__ float ul[128];
  const int t = threadIdx.x;
  const int cc = blockIdx.x, rc = blockIdx.y, r0 = rc*128;
  if (t < 128) ul[t] = u[r0 + t];
  __syncthreads();
  float a0=0.f, a1=0.f, a2=0.f, a3=0.f;
  const U32* p = K2 + (size_t)r0*(NN/2) + cc*512 + t*2;
  #pragma unroll 8
  for (int i = 0; i < 128; ++i){
    uint2 w = *(const uint2*)(p + (size_t)i*(NN/2));
    float ui = ul[i];
    a0 = fmaf(bflo(w.x), ui, a0);
    a1 = fmaf(bfhi(w.x), ui, a1);
    a2 = fmaf(bflo(w.y), ui, a2);
    a3 = fmaf(bfhi(w.y), ui, a3);
  }
  *(float4*)(part + (size_t)rc*NN + cc*1024 + t*4) = make_float4(a0,a1,a2,a3);
}

// v[j] = 1/sum part
__global__ __launch_bounds__(128) void k_vfin(const float* __restrict__ part, float* __restrict__ v){
  const int c = blockIdx.x*128 + threadIdx.x;
  float s = 0.f;
  #pragma unroll 8
  for (int k = 0; k < 64; ++k) s += part[(size_t)k*NN + c];
  v[c] = rcpf(s);
}

// row pass; v staged in LDS with XOR-swizzled float4 slots (kills 16-way bank conflict:
// V' = V ^ ((V>>3)&7) spreads any 16 consecutive lanes 2-per-bank). u = 1/(K v).
__global__ __launch_bounds__(512) void k_row(const U32* __restrict__ K2, const float* __restrict__ v,
                                             float* __restrict__ u){
  __shared__ float4 vl4[2048];
  const int t = threadIdx.x;
  #pragma unroll
  for (int h = 0; h < 4; ++h){
    int V = t + 512*h;
    vl4[V ^ ((V >> 3) & 7)] = ((const float4*)v)[V];
  }
  __syncthreads();
  const int wv = t >> 6, ln = t & 63;
  const int r = blockIdx.x*8 + wv;
  const uint4* p = (const uint4*)(K2 + (size_t)r*(NN/2));
  float s = 0.f;
  #pragma unroll 4
  for (int k = 0; k < 16; ++k){
    uint4 w = p[k*64 + ln];
    int V = (k*64 + ln)*2;
    int msk = (V >> 3) & 7;            // same for V and V+1 (V even)
    float4 v0 = vl4[V ^ msk];
    float4 v1 = vl4[(V + 1) ^ msk];
    s = fmaf(bflo(w.x), v0.x, s); s = fmaf(bfhi(w.x), v0.y, s);
    s = fmaf(bflo(w.y), v0.z, s); s = fmaf(bfhi(w.y), v0.w, s);
    s = fmaf(bflo(w.z), v1.x, s); s = fmaf(bfhi(w.z), v1.y, s);
    s = fmaf(bflo(w.w), v1.z, s); s = fmaf(bfhi(w.w), v1.w, s);
  }
  #pragma unroll
  for (int o = 32; o; o >>= 1) s += __shfl_xor(s, o);
  if (ln == 0) u[r] = rcpf(s);
}

// ---------------- epilogue (verified in R6) ----------------
// At_h/At_l[d][j] = bf16 hi/lo split of v_j * A[j][d]  (transposed, j-fast)
__global__ __launch_bounds__(256) void k_At(const float* __restrict__ A, const float* __restrict__ v,
                                            U16* __restrict__ Ath, U16* __restrict__ Atl){
  __shared__ float Ts[64][65];
  const int t = threadIdx.x;
  const int d0 = blockIdx.x*64, j0 = blockIdx.y*64;
  {
    const int r = t >> 2, cs = (t & 3)*16;
    const float vj = v[j0 + r];
    #pragma unroll
    for (int e=0;e<4;++e){
      float4 a4 = *(const float4*)(A + (size_t)(j0+r)*DD + d0 + cs + e*4);
      Ts[r][cs+e*4+0]=a4.x*vj; Ts[r][cs+e*4+1]=a4.y*vj;
      Ts[r][cs+e*4+2]=a4.z*vj; Ts[r][cs+e*4+3]=a4.w*vj;
    }
  }
  __syncthreads();
  {
    const int dr = t >> 2, jseg = t & 3;
    U16 hh[16], ll[16];
    #pragma unroll
    for (int e=0;e<16;++e){
      float x = Ts[jseg*16+e][dr];
      U16 h = tobf(x);
      hh[e] = h;
      ll[e] = tobf(x - __uint_as_float(((U32)h) << 16));
    }
    size_t off = (size_t)(d0+dr)*NN + j0 + jseg*16;
    *(uint4*)(Ath + off)     = *(const uint4*)&hh[0];
    *(uint4*)(Ath + off + 8) = *(const uint4*)&hh[8];
    *(uint4*)(Atl + off)     = *(const uint4*)&ll[0];
    *(uint4*)(Atl + off + 8) = *(const uint4*)&ll[8];
  }
}

// MFMA out-GEMM: aligned_A[i][d] = u_i * sum_j K'[i][j] * (At_h+At_l)[d][j]
__global__ __launch_bounds__(512) void k_outA(const U16* __restrict__ Kp,
                                              const U16* __restrict__ Ath, const U16* __restrict__ Atl,
                                              const float* __restrict__ u, float* __restrict__ outA){
  __shared__ U16 Ks[128][40];
  __shared__ U16 Ah[192][40];
  __shared__ U16 Al[192][40];
  const int t = threadIdx.x;
  const int i0 = blockIdx.y*128, d0 = blockIdx.x*192;
  const int w  = t >> 6, lane = t & 63;
  const int wm = w >> 1, wn = w & 1;
  const int l15 = lane & 15, lhi = lane >> 4;
  f32x4 acc[2][6];
  #pragma unroll
  for (int fm=0;fm<2;++fm)
    #pragma unroll
    for (int fn=0;fn<6;++fn) acc[fm][fn] = (f32x4){0.f,0.f,0.f,0.f};

  const int sr = t >> 2, sseg = t & 3;
  for (int j0 = 0; j0 < NN; j0 += 32){
    __syncthreads();
    {
      uint4 kw = *(const uint4*)(Kp + (size_t)(i0+sr)*NN + j0 + sseg*8);
      *(uint4*)&Ks[sr][sseg*8] = kw;
      #pragma unroll
      for (int uu=0; uu<3; ++uu){
        int id = t + 512*uu;
        if (id < 768){
          int r = id >> 2, seg = id & 3;
          uint4 aw = *(const uint4*)(Ath + (size_t)(d0+r)*NN + j0 + seg*8);
          *(uint4*)&Ah[r][seg*8] = aw;
        } else {
          int rid = id - 768;
          int r = rid >> 2, seg = rid & 3;
          uint4 aw = *(const uint4*)(Atl + (size_t)(d0+r)*NN + j0 + seg*8);
          *(uint4*)&Al[r][seg*8] = aw;
        }
      }
    }
    __syncthreads();
    short8 af[2];
    #pragma unroll
    for (int fm=0;fm<2;++fm)
      af[fm] = *(const short8*)&Ks[wm*32 + fm*16 + l15][lhi*8];
    #pragma unroll
    for (int fn=0;fn<6;++fn){
      short8 bh = *(const short8*)&Ah[wn*96 + fn*16 + l15][lhi*8];
      short8 bl = *(const short8*)&Al[wn*96 + fn*16 + l15][lhi*8];
      #pragma unroll
      for (int fm=0;fm<2;++fm){
        acc[fm][fn] = __builtin_amdgcn_mfma_f32_16x16x32_bf16(af[fm], bh, acc[fm][fn], 0, 0, 0);
        acc[fm][fn] = __builtin_amdgcn_mfma_f32_16x16x32_bf16(af[fm], bl, acc[fm][fn], 0, 0, 0);
      }
    }
  }
  float us[2][4];
  #pragma unroll
  for (int fm=0;fm<2;++fm)
    #pragma unroll
    for (int r=0;r<4;++r) us[fm][r] = u[i0 + wm*32 + fm*16 + lhi*4 + r];
  #pragma unroll
  for (int fm=0;fm<2;++fm)
    #pragma unroll
    for (int fn=0;fn<6;++fn)
      #pragma unroll
      for (int r=0;r<4;++r){
        int i = i0 + wm*32 + fm*16 + lhi*4 + r;
        int d = d0 + wn*96 + fn*16 + l15;
        outA[(size_t)i*DD + d] = acc[fm][fn][r] * us[fm][r];
      }
}

// VALU out-GEMM: aligned_B[j][d] = v_j * sum_i (u_i K'[i][j]) * B[i][d]
__global__ __launch_bounds__(256) void k_outB(const U16* __restrict__ Kp, const float* __restrict__ B,
                                              const float* __restrict__ u, const float* __restrict__ v,
                                              float* __restrict__ outB){
  __shared__ float Tt[64][65];
  const int t = threadIdx.x;
  const int j0t = blockIdx.y*64, d0 = blockIdx.x*128;
  const int jc = t & 63, ig = t >> 6;
  const int dg = t & 31, jg = t >> 5;
  float4 acc[8];
  #pragma unroll
  for (int m=0;m<8;m++) acc[m] = make_float4(0.f,0.f,0.f,0.f);
  for (int i0 = 0; i0 < NN; i0 += 64){
    __syncthreads();
    #pragma unroll
    for (int m=0;m<16;m++){
      int i = i0 + ig*16 + m;
      U32 kb = ((U32)Kp[(size_t)i*NN + j0t + jc]) << 16;
      Tt[jc][ig*16+m] = __uint_as_float(kb) * u[i];
    }
    __syncthreads();
    #pragma unroll 4
    for (int ii = 0; ii < 64; ++ii){
      float4 b4 = *(const float4*)(B + (size_t)(i0+ii)*DD + d0 + dg*4);
      #pragma unroll
      for (int m=0;m<8;m++){
        float tv = Tt[jg*8+m][ii];
        acc[m].x = fmaf(tv, b4.x, acc[m].x);
        acc[m].y = fmaf(tv, b4.y, acc[m].y);
        acc[m].z = fmaf(tv, b4.z, acc[m].z);
        acc[m].w = fmaf(tv, b4.w, acc[m].w);
      }
    }
  }
  #pragma unroll
  for (int m=0;m<8;m++){
    int j = j0t + jg*8 + m;
    float vj = v[j];
    acc[m].x *= vj; acc[m].y *= vj; acc[m].z *= vj; acc[m].w *= vj;
    *(float4*)(outB + (size_t)j*DD + d0 + dg*4) = acc[m];
  }
}

extern "C" void kernel_launch(void* const* d_in, const int* in_sizes, int n_in,
                              void* d_out, int out_size, void* d_ws, size_t ws_size,
                              hipStream_t stream) {
  const float* A = (const float*)d_in[0];
  const float* B = (const float*)d_in[1];
  float* out = (float*)d_out;
  char* ws = (char*)d_ws;
  U16*  q     = (U16*) (ws);                          // 134217728 B
  float* part = (float*)(ws + 134217728);             // 2 MB
  float* u    = (float*)(ws + 136314880);
  float* v    = (float*)(ws + 136347648);
  float* sqA  = (float*)(ws + 136380416);
  float* sqB  = (float*)(ws + 136413184);
  U32*  slots = (U32*) (ws + 136445952);
  // At scratch lives in d_out's second half (dead until k_outB writes it):
  U16* Ath = (U16*)(out + (size_t)NN*DD);
  U16* Atl = Ath + (size_t)NN*DD;

  k_init<<<1, 64, 0, stream>>>(slots);
  k_useti<<<32, 256, 0, stream>>>(u);
  k_sqsum<<<4096, 256, 0, stream>>>(A, B, sqA, sqB, slots);
  k_dist<<<dim3(64,64), 256, 0, stream>>>(A, B, q, sqA, sqB, slots);
  k_buildK<<<32768, 256, 0, stream>>>((U32*)q, slots);

  for (int it = 0; it < 200; ++it){
    k_col<<<dim3(8,64), 256, 0, stream>>>((const U32*)q, u, part);
    k_vfin<<<64, 128, 0, stream>>>(part, v);
    k_row<<<1024, 512, 0, stream>>>((const U32*)q, v, u);
  }

  k_At<<<dim3(12,128), 256, 0, stream>>>(A, v, Ath, Atl);
  k_outA<<<dim3(4,64), 512, 0, stream>>>(q, Ath, Atl, u, out);
  k_outB<<<dim3(6,128), 256, 0, stream>>>(q, B, u, v, out + (size_t)NN*DD);
}

// Round 10
// 13081.863 us; speedup vs baseline: 2.3910x; 1.0202x over previous
//
#include <hip/hip_runtime.h>
#include <stdint.h>

#define NN 8192
#define DD 768
#define LOG2E 1.4426950408889634f

typedef unsigned int  U32;
typedef unsigned short U16;
typedef __attribute__((ext_vector_type(8))) short short8;
typedef __attribute__((ext_vector_type(4))) float f32x4;

__device__ __forceinline__ U32 fkey(float x){
  U32 u = __float_as_uint(x);
  return (u & 0x80000000u) ? ~u : (u | 0x80000000u);
}
__device__ __forceinline__ float funkey(U32 k){
  return __uint_as_float((k & 0x80000000u) ? (k ^ 0x80000000u) : ~k);
}
__device__ __forceinline__ float ex2(float x){ return __builtin_amdgcn_exp2f(x); }
__device__ __forceinline__ float rcpf(float x){ return __builtin_amdgcn_rcpf(x); }
__device__ __forceinline__ float bflo(U32 w){ return __uint_as_float(w << 16); }
__device__ __forceinline__ float bfhi(U32 w){ return __uint_as_float(w & 0xFFFF0000u); }
__device__ __forceinline__ U16 tobf(float x){
  U32 a = __float_as_uint(x);
  return (U16)((a + 0x7FFFu + ((a >> 16) & 1u)) >> 16);
}
__device__ __forceinline__ U32 packbf(float lo, float hi){
  U32 a = __float_as_uint(lo), b = __float_as_uint(hi);
  a = a + 0x7FFFu + ((a >> 16) & 1u);
  b = b + 0x7FFFu + ((b >> 16) & 1u);
  return (a >> 16) | (b & 0xFFFF0000u);
}

// slots: 0 qmax 1 qmin 2 maxsqA key 3 maxsqB key
__global__ __launch_bounds__(64) void k_init(U32* slots){
  if (threadIdx.x == 0){ slots[0]=0u; slots[1]=0xFFFFFFFFu; slots[2]=0u; slots[3]=0u; }
}

__global__ __launch_bounds__(256) void k_sqsum(const float* __restrict__ A, const float* __restrict__ B,
                                               float* sqA, float* sqB, U32* slots){
  int wv = threadIdx.x >> 6, ln = threadIdx.x & 63;
  int row = blockIdx.x*4 + wv;
  const float* src = A; float* dst = sqA; U32* slot = slots + 2; int r = row;
  if (row >= NN){ src = B; dst = sqB; slot = slots + 3; r = row - NN; }
  const float* p = src + (size_t)r * DD;
  float s = 0.f;
  #pragma unroll
  for (int m = 0; m < DD/64; ++m){ float v = p[ln + 64*m]; s = fmaf(v, v, s); }
  #pragma unroll
  for (int o = 32; o; o >>= 1) s += __shfl_xor(s, o);
  if (ln == 0){ dst[r] = s; atomicMax(slot, fkey(s)); }
}

// 128x128 tile fp32 Gram -> dist -> u16 quantize; track qmax/qmin
__global__ __launch_bounds__(256) void k_dist(const float* __restrict__ A, const float* __restrict__ B,
                                              U16* __restrict__ q, const float* __restrict__ sqA,
                                              const float* __restrict__ sqB, U32* slots){
  __shared__ float As[16][128], Bs[16][128];
  __shared__ U32 redmx[4], redmn[4];
  const int t = threadIdx.x;
  const int i0 = blockIdx.y*128, j0 = blockIdx.x*128;
  const float S = 65535.f / (sqrtf(funkey(slots[2])) + sqrtf(funkey(slots[3])));
  float acc[8][8];
  #pragma unroll
  for (int m=0;m<8;m++)
    #pragma unroll
    for (int n=0;n<8;n++) acc[m][n] = 0.f;
  const int lr = t >> 1, lk = (t & 1)*8;
  const float* pa = A + (size_t)(i0+lr)*DD + lk;
  const float* pb = B + (size_t)(j0+lr)*DD + lk;
  const int tx = t & 15, ty = t >> 4;
  for (int k0 = 0; k0 < DD; k0 += 16){
    __syncthreads();
    float4 a0 = *(const float4*)(pa + k0);
    float4 a1 = *(const float4*)(pa + k0 + 4);
    float4 b0 = *(const float4*)(pb + k0);
    float4 b1 = *(const float4*)(pb + k0 + 4);
    As[lk+0][lr]=a0.x; As[lk+1][lr]=a0.y; As[lk+2][lr]=a0.z; As[lk+3][lr]=a0.w;
    As[lk+4][lr]=a1.x; As[lk+5][lr]=a1.y; As[lk+6][lr]=a1.z; As[lk+7][lr]=a1.w;
    Bs[lk+0][lr]=b0.x; Bs[lk+1][lr]=b0.y; Bs[lk+2][lr]=b0.z; Bs[lk+3][lr]=b0.w;
    Bs[lk+4][lr]=b1.x; Bs[lk+5][lr]=b1.y; Bs[lk+6][lr]=b1.z; Bs[lk+7][lr]=b1.w;
    __syncthreads();
    #pragma unroll
    for (int kk = 0; kk < 16; ++kk){
      float4 am0 = *(const float4*)&As[kk][ty*8];
      float4 am1 = *(const float4*)&As[kk][ty*8+4];
      float4 bn0 = *(const float4*)&Bs[kk][tx*8];
      float4 bn1 = *(const float4*)&Bs[kk][tx*8+4];
      float ar[8] = {am0.x,am0.y,am0.z,am0.w,am1.x,am1.y,am1.z,am1.w};
      float br[8] = {bn0.x,bn0.y,bn0.z,bn0.w,bn1.x,bn1.y,bn1.z,bn1.w};
      #pragma unroll
      for (int m=0;m<8;m++)
        #pragma unroll
        for (int n=0;n<8;n++) acc[m][n] = fmaf(ar[m], br[n], acc[m][n]);
    }
  }
  U32 bmax = 0u, bmin = 0xFFFFu;
  #pragma unroll
  for (int m=0;m<8;m++){
    int i = i0 + ty*8 + m;
    float sa = sqA[i];
    U16 pk[8] __attribute__((aligned(16)));
    #pragma unroll
    for (int n=0;n<8;n++){
      int j = j0 + tx*8 + n;
      float sq = sa + sqB[j] - 2.f*acc[m][n];
      float d = sqrtf(fmaxf(sq, 0.f));
      d = fmaxf(d, 1e-6f);
      U32 qv = (U32)rintf(d * S);
      if (qv > 65535u) qv = 65535u;
      bmax = bmax > qv ? bmax : qv;
      bmin = bmin < qv ? bmin : qv;
      pk[n] = (U16)qv;
    }
    *(uint4*)(q + (size_t)i*NN + j0 + tx*8) = *(const uint4*)pk;
  }
  #pragma unroll
  for (int o=32;o;o>>=1){
    U32 om = __shfl_xor(bmax, o); bmax = bmax > om ? bmax : om;
    U32 on = __shfl_xor(bmin, o); bmin = bmin < on ? bmin : on;
  }
  if ((t & 63) == 0){ redmx[t>>6] = bmax; redmn[t>>6] = bmin; }
  __syncthreads();
  if (t == 0){
    U32 mx = redmx[0], mn = redmn[0];
    #pragma unroll
    for (int i=1;i<4;i++){ mx = mx > redmx[i] ? mx : redmx[i]; mn = mn < redmn[i] ? mn : redmn[i]; }
    atomicMax(slots+0, mx); atomicMin(slots+1, mn);
  }
}

// in-place u16 q -> bf16 K' = exp(logK + s), s = 50(1+qmin/qmax) ln-units
__global__ __launch_bounds__(256) void k_buildK(U32* K2, const U32* __restrict__ slots){
  const float qmaxf = (float)slots[0];
  const float r0n = (float)slots[1] / qmaxf;
  const float k1 = -100.f*LOG2E/qmaxf;
  const float c2 = 50.f*(1.f + r0n)*LOG2E;
  const float tcl = -1e-4f*LOG2E;
  size_t base = ((size_t)blockIdx.x*256 + threadIdx.x)*4;
  uint4 w = *(uint4*)(K2 + base);
  U32 r[4];
  U32 in[4] = {w.x, w.y, w.z, w.w};
  #pragma unroll
  for (int k=0;k<4;++k){
    float ql = (float)(in[k] & 0xFFFFu);
    float qh = (float)(in[k] >> 16);
    float el = ex2(fminf(ql*k1, tcl) + c2);
    float eh = ex2(fminf(qh*k1, tcl) + c2);
    r[k] = packbf(el, eh);
  }
  *(uint4*)(K2 + base) = make_uint4(r[0], r[1], r[2], r[3]);
}

// ---------------- fused Sinkhorn sweep ----------------
// Block rc owns rows [16rc,16rc+16); thread owns cols {s*2048 + t*8 + e}.
// Per 4-row group: row-dots vs v (LDS, XOR-swizzled) -> wave reduce -> 1 barrier
// -> uu = rcp(rowsum) (also written to u[]) -> col partials from SAME registers.
// FIRST=1: uu = 1/8192, no v read, no barriers.
template<int FIRST>
__global__ __launch_bounds__(256) void k_fused(const uint4* __restrict__ Kp,
                                               const float* __restrict__ v,
                                               float* __restrict__ u,
                                               float* __restrict__ part){
  __shared__ float4 vl4[2048];          // 32 KB
  __shared__ float ws[2][4][4];
  const int t = threadIdx.x;
  const int rc = blockIdx.x;
  const int r0 = rc*16;
  const int wv = t >> 6, ln = t & 63;
  if (!FIRST){
    #pragma unroll
    for (int h = 0; h < 8; ++h){
      int V = t + 256*h;
      vl4[V ^ ((V >> 3) & 7)] = ((const float4*)v)[V];
    }
    __syncthreads();
  }
  float a[4][8];
  #pragma unroll
  for (int s=0;s<4;++s)
    #pragma unroll
    for (int e=0;e<8;++e) a[s][e] = 0.f;

  #pragma unroll
  for (int g=0; g<4; ++g){
    uint4 kw[4][4];                     // [row in group][strip]
    #pragma unroll
    for (int rr=0; rr<4; ++rr)
      #pragma unroll
      for (int s=0; s<4; ++s)
        kw[rr][s] = Kp[(size_t)(r0 + g*4 + rr)*1024 + s*256 + t];
    float uu[4];
    if (!FIRST){
      float d[4] = {0.f,0.f,0.f,0.f};
      #pragma unroll
      for (int s=0; s<4; ++s){
        int V = s*512 + t*2;
        int msk = (V >> 3) & 7;         // same for V and V+1 (V even)
        float4 v0 = vl4[V ^ msk];
        float4 v1 = vl4[(V + 1) ^ msk];
        #pragma unroll
        for (int rr=0; rr<4; ++rr){
          uint4 w = kw[rr][s];
          d[rr]=fmaf(bflo(w.x),v0.x,d[rr]); d[rr]=fmaf(bfhi(w.x),v0.y,d[rr]);
          d[rr]=fmaf(bflo(w.y),v0.z,d[rr]); d[rr]=fmaf(bfhi(w.y),v0.w,d[rr]);
          d[rr]=fmaf(bflo(w.z),v1.x,d[rr]); d[rr]=fmaf(bfhi(w.z),v1.y,d[rr]);
          d[rr]=fmaf(bflo(w.w),v1.z,d[rr]); d[rr]=fmaf(bfhi(w.w),v1.w,d[rr]);
        }
      }
      #pragma unroll
      for (int o=32; o; o>>=1){
        #pragma unroll
        for (int rr=0; rr<4; ++rr) d[rr] += __shfl_xor(d[rr], o);
      }
      if (ln == 0){
        #pragma unroll
        for (int rr=0; rr<4; ++rr) ws[g & 1][rr][wv] = d[rr];
      }
      __syncthreads();
      #pragma unroll
      for (int rr=0; rr<4; ++rr)
        uu[rr] = rcpf(ws[g&1][rr][0] + ws[g&1][rr][1] + ws[g&1][rr][2] + ws[g&1][rr][3]);
    } else {
      #pragma unroll
      for (int rr=0; rr<4; ++rr) uu[rr] = 1.0f/8192.0f;
    }
    if (t < 4) u[r0 + g*4 + t] = uu[t];
    #pragma unroll
    for (int rr=0; rr<4; ++rr){
      float ur = uu[rr];
      #pragma unroll
      for (int s=0; s<4; ++s){
        uint4 w = kw[rr][s];
        a[s][0]=fmaf(bflo(w.x),ur,a[s][0]); a[s][1]=fmaf(bfhi(w.x),ur,a[s][1]);
        a[s][2]=fmaf(bflo(w.y),ur,a[s][2]); a[s][3]=fmaf(bfhi(w.y),ur,a[s][3]);
        a[s][4]=fmaf(bflo(w.z),ur,a[s][4]); a[s][5]=fmaf(bfhi(w.z),ur,a[s][5]);
        a[s][6]=fmaf(bflo(w.w),ur,a[s][6]); a[s][7]=fmaf(bfhi(w.w),ur,a[s][7]);
      }
    }
  }
  #pragma unroll
  for (int s=0; s<4; ++s){
    float* pp = part + (size_t)rc*NN + s*2048 + t*8;
    *(float4*)pp     = make_float4(a[s][0],a[s][1],a[s][2],a[s][3]);
    *(float4*)(pp+4) = make_float4(a[s][4],a[s][5],a[s][6],a[s][7]);
  }
}

// v[c] = 1 / sum over 512 chunks; 2-stage (8-way split per column + LDS reduce)
__global__ __launch_bounds__(256) void k_vfin(const float* __restrict__ part, float* __restrict__ v){
  __shared__ float red[32][9];
  const int t = threadIdx.x;
  const int ci = t & 31, kk = t >> 5;   // kk in 0..7
  const int c = blockIdx.x*32 + ci;
  float s = 0.f;
  #pragma unroll 8
  for (int m = 0; m < 64; ++m) s += part[(size_t)(kk*64 + m)*NN + c];
  red[ci][kk] = s;
  __syncthreads();
  if (t < 32){
    float q2 = 0.f;
    #pragma unroll
    for (int k=0;k<8;++k) q2 += red[t][k];
    v[blockIdx.x*32 + t] = rcpf(q2);
  }
}

// ---------------- epilogue (verified R6/R8) ----------------
__global__ __launch_bounds__(256) void k_At(const float* __restrict__ A, const float* __restrict__ v,
                                            U16* __restrict__ Ath, U16* __restrict__ Atl){
  __shared__ float Ts[64][65];
  const int t = threadIdx.x;
  const int d0 = blockIdx.x*64, j0 = blockIdx.y*64;
  {
    const int r = t >> 2, cs = (t & 3)*16;
    const float vj = v[j0 + r];
    #pragma unroll
    for (int e=0;e<4;++e){
      float4 a4 = *(const float4*)(A + (size_t)(j0+r)*DD + d0 + cs + e*4);
      Ts[r][cs+e*4+0]=a4.x*vj; Ts[r][cs+e*4+1]=a4.y*vj;
      Ts[r][cs+e*4+2]=a4.z*vj; Ts[r][cs+e*4+3]=a4.w*vj;
    }
  }
  __syncthreads();
  {
    const int dr = t >> 2, jseg = t & 3;
    U16 hh[16], ll[16];
    #pragma unroll
    for (int e=0;e<16;++e){
      float x = Ts[jseg*16+e][dr];
      U16 h = tobf(x);
      hh[e] = h;
      ll[e] = tobf(x - __uint_as_float(((U32)h) << 16));
    }
    size_t off = (size_t)(d0+dr)*NN + j0 + jseg*16;
    *(uint4*)(Ath + off)     = *(const uint4*)&hh[0];
    *(uint4*)(Ath + off + 8) = *(const uint4*)&hh[8];
    *(uint4*)(Atl + off)     = *(const uint4*)&ll[0];
    *(uint4*)(Atl + off + 8) = *(const uint4*)&ll[8];
  }
}

__global__ __launch_bounds__(512) void k_outA(const U16* __restrict__ Kp,
                                              const U16* __restrict__ Ath, const U16* __restrict__ Atl,
                                              const float* __restrict__ u, float* __restrict__ outA){
  __shared__ U16 Ks[128][40];
  __shared__ U16 Ah[192][40];
  __shared__ U16 Al[192][40];
  const int t = threadIdx.x;
  const int i0 = blockIdx.y*128, d0 = blockIdx.x*192;
  const int w  = t >> 6, lane = t & 63;
  const int wm = w >> 1, wn = w & 1;
  const int l15 = lane & 15, lhi = lane >> 4;
  f32x4 acc[2][6];
  #pragma unroll
  for (int fm=0;fm<2;++fm)
    #pragma unroll
    for (int fn=0;fn<6;++fn) acc[fm][fn] = (f32x4){0.f,0.f,0.f,0.f};

  const int sr = t >> 2, sseg = t & 3;
  for (int j0 = 0; j0 < NN; j0 += 32){
    __syncthreads();
    {
      uint4 kw = *(const uint4*)(Kp + (size_t)(i0+sr)*NN + j0 + sseg*8);
      *(uint4*)&Ks[sr][sseg*8] = kw;
      #pragma unroll
      for (int uu=0; uu<3; ++uu){
        int id = t + 512*uu;
        if (id < 768){
          int r = id >> 2, seg = id & 3;
          uint4 aw = *(const uint4*)(Ath + (size_t)(d0+r)*NN + j0 + seg*8);
          *(uint4*)&Ah[r][seg*8] = aw;
        } else {
          int rid = id - 768;
          int r = rid >> 2, seg = rid & 3;
          uint4 aw = *(const uint4*)(Atl + (size_t)(d0+r)*NN + j0 + seg*8);
          *(uint4*)&Al[r][seg*8] = aw;
        }
      }
    }
    __syncthreads();
    short8 af[2];
    #pragma unroll
    for (int fm=0;fm<2;++fm)
      af[fm] = *(const short8*)&Ks[wm*32 + fm*16 + l15][lhi*8];
    #pragma unroll
    for (int fn=0;fn<6;++fn){
      short8 bh = *(const short8*)&Ah[wn*96 + fn*16 + l15][lhi*8];
      short8 bl = *(const short8*)&Al[wn*96 + fn*16 + l15][lhi*8];
      #pragma unroll
      for (int fm=0;fm<2;++fm){
        acc[fm][fn] = __builtin_amdgcn_mfma_f32_16x16x32_bf16(af[fm], bh, acc[fm][fn], 0, 0, 0);
        acc[fm][fn] = __builtin_amdgcn_mfma_f32_16x16x32_bf16(af[fm], bl, acc[fm][fn], 0, 0, 0);
      }
    }
  }
  float us[2][4];
  #pragma unroll
  for (int fm=0;fm<2;++fm)
    #pragma unroll
    for (int r=0;r<4;++r) us[fm][r] = u[i0 + wm*32 + fm*16 + lhi*4 + r];
  #pragma unroll
  for (int fm=0;fm<2;++fm)
    #pragma unroll
    for (int fn=0;fn<6;++fn)
      #pragma unroll
      for (int r=0;r<4;++r){
        int i = i0 + wm*32 + fm*16 + lhi*4 + r;
        int d = d0 + wn*96 + fn*16 + l15;
        outA[(size_t)i*DD + d] = acc[fm][fn][r] * us[fm][r];
      }
}

__global__ __launch_bounds__(256) void k_outB(const U16* __restrict__ Kp, const float* __restrict__ B,
                                              const float* __restrict__ u, const float* __restrict__ v,
                                              float* __restrict__ outB){
  __shared__ float Tt[64][65];
  const int t = threadIdx.x;
  const int j0t = blockIdx.y*64, d0 = blockIdx.x*128;
  const int jc = t & 63, ig = t >> 6;
  const int dg = t & 31, jg = t >> 5;
  float4 acc[8];
  #pragma unroll
  for (int m=0;m<8;m++) acc[m] = make_float4(0.f,0.f,0.f,0.f);
  for (int i0 = 0; i0 < NN; i0 += 64){
    __syncthreads();
    #pragma unroll
    for (int m=0;m<16;m++){
      int i = i0 + ig*16 + m;
      U32 kb = ((U32)Kp[(size_t)i*NN + j0t + jc]) << 16;
      Tt[jc][ig*16+m] = __uint_as_float(kb) * u[i];
    }
    __syncthreads();
    #pragma unroll 4
    for (int ii = 0; ii < 64; ++ii){
      float4 b4 = *(const float4*)(B + (size_t)(i0+ii)*DD + d0 + dg*4);
      #pragma unroll
      for (int m=0;m<8;m++){
        float tv = Tt[jg*8+m][ii];
        acc[m].x = fmaf(tv, b4.x, acc[m].x);
        acc[m].y = fmaf(tv, b4.y, acc[m].y);
        acc[m].z = fmaf(tv, b4.z, acc[m].z);
        acc[m].w = fmaf(tv, b4.w, acc[m].w);
      }
    }
  }
  #pragma unroll
  for (int m=0;m<8;m++){
    int j = j0t + jg*8 + m;
    float vj = v[j];
    acc[m].x *= vj; acc[m].y *= vj; acc[m].z *= vj; acc[m].w *= vj;
    *(float4*)(outB + (size_t)j*DD + d0 + dg*4) = acc[m];
  }
}

extern "C" void kernel_launch(void* const* d_in, const int* in_sizes, int n_in,
                              void* d_out, int out_size, void* d_ws, size_t ws_size,
                              hipStream_t stream) {
  const float* A = (const float*)d_in[0];
  const float* B = (const float*)d_in[1];
  float* out = (float*)d_out;
  char* ws = (char*)d_ws;
  U16*  q     = (U16*) (ws);                          // 134217728 B
  float* u    = (float*)(ws + 136314880);
  float* v    = (float*)(ws + 136347648);
  float* sqA  = (float*)(ws + 136380416);
  float* sqB  = (float*)(ws + 136413184);
  U32*  slots = (U32*) (ws + 136445952);
  // part[512][8192] f32 = 16.8 MB in d_out's first region (dead until k_outA);
  // Ath/Atl in d_out's second half (dead until k_outB).
  float* part = out;
  U16* Ath = (U16*)(out + (size_t)NN*DD);
  U16* Atl = Ath + (size_t)NN*DD;

  k_init<<<1, 64, 0, stream>>>(slots);
  k_sqsum<<<4096, 256, 0, stream>>>(A, B, sqA, sqB, slots);
  k_dist<<<dim3(64,64), 256, 0, stream>>>(A, B, q, sqA, sqB, slots);
  k_buildK<<<32768, 256, 0, stream>>>((U32*)q, slots);

  const uint4* Kp4 = (const uint4*)q;
  k_fused<1><<<512, 256, 0, stream>>>(Kp4, v, u, part);
  for (int it = 0; it < 200; ++it){
    k_vfin<<<256, 256, 0, stream>>>(part, v);
    k_fused<0><<<512, 256, 0, stream>>>(Kp4, v, u, part);
  }

  k_At<<<dim3(12,128), 256, 0, stream>>>(A, v, Ath, Atl);
  k_outA<<<dim3(4,64), 512, 0, stream>>>(q, Ath, Atl, u, out);
  k_outB<<<dim3(6,128), 256, 0, stream>>>(q, B, u, v, out + (size_t)NN*DD);
}